// Round 5
// baseline (76.400 us; speedup 1.0000x reference)
//
#include <hip/hip_runtime.h>
#include <math.h>

constexpr int B_ = 64, Q_ = 900, N_ = 100, C_ = 256;
constexpr float EPSF = 1e-6f;
constexpr float BOX_W = 5.0f, GIOU_W = 2.0f, CLS_W = 1.0f;
constexpr int KP = 15;  // preds per lane: 64 lanes * 15 >= 900
constexpr int K_ = 8;   // candidate depth per column
typedef unsigned long long u64;

__device__ __forceinline__ float giou_f(float px0, float py0, float px1, float py1, float pa,
                                        float tx0, float ty0, float tx1, float ty1, float ta) {
    float ltx = fmaxf(px0, tx0), lty = fmaxf(py0, ty0);
    float rbx = fminf(px1, tx1), rby = fminf(py1, ty1);
    float w = fmaxf(rbx - ltx, 0.0f), h = fmaxf(rby - lty, 0.0f);
    float inter = w * h;
    float uni = pa + ta - inter;
    float iou = inter / (uni + EPSF);
    float ex0 = fminf(px0, tx0), ey0 = fminf(py0, ty0);
    float ex1 = fmaxf(px1, tx1), ey1 = fmaxf(py1, ty1);
    float ew = fmaxf(ex1 - ex0, 0.0f), eh = fmaxf(ey1 - ey0, 0.0f);
    float earea = ew * eh;
    return iou - (earea - uni) / (earea + EPSF);
}

// order-preserving float->uint; key = (ord << 32) | ~q  => u64 max == (max value, min index)
__device__ __forceinline__ unsigned int f2ord(float f) {
    unsigned int u = __float_as_uint(f);
    return (u & 0x80000000u) ? ~u : (u | 0x80000000u);
}
__device__ __forceinline__ u64 mkkey(float g, int q) {
    return ((u64)f2ord(g) << 32) | (unsigned int)(~(unsigned int)q);
}
__device__ __forceinline__ int keyidx(u64 k) { return (int)(~(unsigned int)k); }
__device__ __forceinline__ u64 umax64(u64 a, u64 b) { return a > b ? a : b; }
__device__ __forceinline__ u64 umin64(u64 a, u64 b) { return a > b ? b : a; }

// ---------------- kernel 1: per-column exact top-8 ----------------
// 1600 blocks x 256 threads; each wave owns one (b,n) column
__global__ __launch_bounds__(256) void cand_kernel(
    const float* __restrict__ pred_boxes,   // [B,Q,4] cxcywh
    const float* __restrict__ target_boxes, // [B,N,4] xyxy
    u64* __restrict__ cands)                // [B*N*8]
{
    const int blk = blockIdx.x;
    const int b = blk / 25;
    const int wave = threadIdx.x >> 6;
    const int lane = threadIdx.x & 63;
    const int n = (blk % 25) * 4 + wave;
    const int bn = b * N_ + n;

    const float* t = target_boxes + (size_t)bn * 4;
    float tx0 = t[0], ty0 = t[1], tx1 = t[2], ty1 = t[3];
    float ta = (tx1 - tx0) * (ty1 - ty0);

    const float4* pbv = (const float4*)(pred_boxes + (size_t)b * Q_ * 4);
    // per-lane sorted (descending) top-8
    u64 a0 = 0, a1 = 0, a2 = 0, a3 = 0, a4 = 0, a5 = 0, a6 = 0, a7 = 0;
    #pragma unroll
    for (int k = 0; k < KP; ++k) {
        int q = lane + (k << 6);
        if (q < Q_) {
            float4 c = pbv[q];
            float x0 = c.x - 0.5f * c.z, y0 = c.y - 0.5f * c.w;
            float x1 = c.x + 0.5f * c.z, y1 = c.y + 0.5f * c.w;
            float pa = (x1 - x0) * (y1 - y0);
            float g = giou_f(x0, y0, x1, y1, pa, tx0, ty0, tx1, ty1, ta);
            u64 kk = mkkey(g, q);
            // branchless sorted insert (bottom-up, uses pre-update neighbors)
            a7 = umax64(a7, umin64(a6, kk));
            a6 = umax64(a6, umin64(a5, kk));
            a5 = umax64(a5, umin64(a4, kk));
            a4 = umax64(a4, umin64(a3, kk));
            a3 = umax64(a3, umin64(a2, kk));
            a2 = umax64(a2, umin64(a1, kk));
            a1 = umax64(a1, umin64(a0, kk));
            a0 = umax64(a0, kk);
        }
    }
    // 8 sequential extractions: butterfly max over lanes' heads, winner pops
    u64* outp = cands + (size_t)bn * K_;
    #pragma unroll
    for (int j = 0; j < K_; ++j) {
        u64 m = a0;
        #pragma unroll
        for (int off = 32; off >= 1; off >>= 1) {
            u64 o = __shfl_xor(m, off);
            if (o > m) m = o;
        }
        if (lane == 0) outp[j] = m;
        if (a0 == m) {  // unique winner (distinct embedded indices)
            a0 = a1; a1 = a2; a2 = a3; a3 = a4; a4 = a5; a5 = a6; a6 = a7; a7 = 0;
        }
    }
}

// ---- kernel 2: register/ballot greedy resolve + box loss + BCE (fused) ----
__global__ __launch_bounds__(256) void fused_kernel(
    const float* __restrict__ pred_boxes,
    const float* __restrict__ pred_logits,
    const float* __restrict__ target_boxes,
    const int*   __restrict__ target_labels,
    const u64*   __restrict__ cands,
    double* __restrict__ partial)   // [B]
{
    const int b = blockIdx.x;
    const int tid = threadIdx.x;
    const int lane = tid & 63;
    const int wid = tid >> 6;

    __shared__ int ms[N_];
    __shared__ int labs[N_];
    __shared__ double red[256];

    if (tid < N_) labs[tid] = target_labels[b * N_ + tid];

    const float4* pbv = (const float4*)(pred_boxes + (size_t)b * Q_ * 4);
    const float4* tbv = (const float4*)(target_boxes + (size_t)b * N_ * 4);

    if (wid == 0) {
        // lane L holds candidates for targets L (A) and L+64 (B)
        int cA[K_], cB[K_];
        {
            const u64* p = cands + (size_t)(b * N_ + lane) * K_;
            #pragma unroll
            for (int j = 0; j < K_; ++j) cA[j] = keyidx(p[j]);
        }
        #pragma unroll
        for (int j = 0; j < K_; ++j) cB[j] = 0;
        if (lane + 64 < N_) {
            const u64* p = cands + (size_t)(b * N_ + lane + 64) * K_;
            #pragma unroll
            for (int j = 0; j < K_; ++j) cB[j] = keyidx(p[j]);
        }
        // targets in registers (lane L: targets L and L+64)
        float4 tA4 = tbv[lane];
        float4 tB4 = (lane + 64 < N_) ? tbv[lane + 64] : make_float4(0.f, 0.f, 0.f, 0.f);

        unsigned int myword = 0u;  // used bits for preds [16*lane, 16*lane+16)
        unsigned int um = 0u;      // used bits among this lane's KP preds

        for (int n = 0; n < N_; ++n) {
            const int s = n & 63;
            const bool hi = (n >= 64);
            int win = -1;
            #pragma unroll
            for (int j = 0; j < K_; ++j) {
                if (win < 0) {
                    int idx = __builtin_amdgcn_readlane(hi ? cB[j] : cA[j], s);
                    bool used = __ballot((lane == (idx >> 4)) && ((myword >> (idx & 15)) & 1u)) != 0ull;
                    if (!used) win = idx;
                }
            }
            if (win < 0) {
                // rare: full masked argmax, boxes straight from L2 (coalesced)
                float tx0 = __shfl(hi ? tB4.x : tA4.x, s);
                float ty0 = __shfl(hi ? tB4.y : tA4.y, s);
                float tx1 = __shfl(hi ? tB4.z : tA4.z, s);
                float ty1 = __shfl(hi ? tB4.w : tA4.w, s);
                float ta = (tx1 - tx0) * (ty1 - ty0);
                u64 bk = 0ull;
                #pragma unroll
                for (int k = 0; k < KP; ++k) {
                    int q = lane + (k << 6);
                    if (q < Q_ && !((um >> k) & 1u)) {
                        float4 c = pbv[q];
                        float x0 = c.x - 0.5f * c.z, y0 = c.y - 0.5f * c.w;
                        float x1 = c.x + 0.5f * c.z, y1 = c.y + 0.5f * c.w;
                        float pa = (x1 - x0) * (y1 - y0);
                        float g = giou_f(x0, y0, x1, y1, pa, tx0, ty0, tx1, ty1, ta);
                        u64 kk = mkkey(g, q);
                        if (kk > bk) bk = kk;
                    }
                }
                #pragma unroll
                for (int off = 32; off >= 1; off >>= 1) {
                    u64 o = __shfl_xor(bk, off);
                    if (o > bk) bk = o;
                }
                win = keyidx(bk);
            }
            if (lane == (win >> 4)) myword |= 1u << (win & 15);
            if (lane == (win & 63)) um |= 1u << (win >> 6);
            if (lane == 0) ms[n] = win;
        }
    }
    __syncthreads();

    double acc = 0.0;

    // box losses: one target per thread (tid < 100), exact original inputs
    if (tid < N_) {
        int q = ms[tid];
        float4 c = pbv[q];
        float4 t4 = tbv[tid];
        float tx0 = t4.x, ty0 = t4.y, tx1 = t4.z, ty1 = t4.w;
        float tcx = (tx0 + tx1) * 0.5f, tcy = (ty0 + ty1) * 0.5f;
        float tw = tx1 - tx0, th = ty1 - ty0;
        float l1 = fabsf(c.x - tcx) + fabsf(c.y - tcy) + fabsf(c.z - tw) + fabsf(c.w - th);
        float x0 = c.x - 0.5f * c.z, y0 = c.y - 0.5f * c.w;
        float x1 = c.x + 0.5f * c.z, y1 = c.y + 0.5f * c.w;
        float pa = (x1 - x0) * (y1 - y0);
        float ta = (tx1 - tx0) * (ty1 - ty0);
        float g = giou_f(x0, y0, x1, y1, pa, tx0, ty0, tx1, ty1, ta);
        acc += (double)(BOX_W * l1) + (double)(GIOU_W * (1.0f - g));
    }

    // BCE: thread tid owns class tid for all 100 rows (coalesced 256B/wave)
    {
        const float* lg = pred_logits + (size_t)b * Q_ * C_ + tid;
        double e0 = 0.0, e1 = 0.0;
        #pragma unroll 4
        for (int n = 0; n < N_; ++n) {
            int q = ms[n];
            int lab = labs[n];
            float x = lg[(size_t)q * C_];
            float tt = (tid == lab) ? 1.0f : 0.0f;
            float term = fmaxf(x, 0.0f) - x * tt + log1pf(expf(-fabsf(x)));
            if (n & 1) e1 += (double)term; else e0 += (double)term;
        }
        acc += (double)CLS_W * (e0 + e1);
    }

    red[tid] = acc;
    __syncthreads();
    #pragma unroll
    for (int s = 128; s >= 1; s >>= 1) {
        if (tid < s) red[tid] += red[tid + s];
        __syncthreads();
    }
    if (tid == 0) partial[b] = red[0];
}

// ---------------- kernel 3: final reduce ----------------
__global__ __launch_bounds__(64) void finalize_kernel(
    const double* __restrict__ partial, float* __restrict__ out)
{
    const int lane = threadIdx.x;
    double acc = partial[lane];
    #pragma unroll
    for (int off = 32; off >= 1; off >>= 1) acc += __shfl_xor(acc, off);
    if (lane == 0) out[0] = (float)(acc / (double)(B_ * N_));
}

extern "C" void kernel_launch(void* const* d_in, const int* in_sizes, int n_in,
                              void* d_out, int out_size, void* d_ws, size_t ws_size,
                              hipStream_t stream) {
    const float* pred_boxes    = (const float*)d_in[0];
    const float* pred_logits   = (const float*)d_in[1];
    const float* target_boxes  = (const float*)d_in[2];
    const int*   target_labels = (const int*)d_in[3];
    float* out = (float*)d_out;

    char* ws = (char*)d_ws;
    u64*    cands   = (u64*)(ws);             // 6400*8*8 = 409600 B
    double* partial = (double*)(ws + 409600); // 64*8

    hipLaunchKernelGGL(cand_kernel, dim3(1600), dim3(256), 0, stream,
                       pred_boxes, target_boxes, cands);
    hipLaunchKernelGGL(fused_kernel, dim3(B_), dim3(256), 0, stream,
                       pred_boxes, pred_logits, target_boxes, target_labels, cands, partial);
    hipLaunchKernelGGL(finalize_kernel, dim3(1), dim3(64), 0, stream, partial, out);
}

// Round 6
// 46.008 us; speedup vs baseline: 1.6606x; 1.6606x over previous
//
#include <hip/hip_runtime.h>
#include <math.h>

constexpr int B_ = 64, Q_ = 900, N_ = 100, C_ = 256;
constexpr float EPSF = 1e-6f;
constexpr float BOX_W = 5.0f, GIOU_W = 2.0f, CLS_W = 1.0f;
constexpr int KP = 15;  // preds per lane: 64 lanes * 15 >= 900
constexpr int K_ = 8;   // candidate depth per column
typedef unsigned long long u64;
typedef unsigned int u32;

__device__ __forceinline__ float giou_f(float px0, float py0, float px1, float py1, float pa,
                                        float tx0, float ty0, float tx1, float ty1, float ta) {
    float ltx = fmaxf(px0, tx0), lty = fmaxf(py0, ty0);
    float rbx = fminf(px1, tx1), rby = fminf(py1, ty1);
    float w = fmaxf(rbx - ltx, 0.0f), h = fmaxf(rby - lty, 0.0f);
    float inter = w * h;
    float uni = pa + ta - inter;
    float iou = inter / (uni + EPSF);
    float ex0 = fminf(px0, tx0), ey0 = fminf(py0, ty0);
    float ex1 = fmaxf(px1, tx1), ey1 = fmaxf(py1, ty1);
    float ew = fmaxf(ex1 - ex0, 0.0f), eh = fmaxf(ey1 - ey0, 0.0f);
    float earea = ew * eh;
    return iou - (earea - uni) / (earea + EPSF);
}

// order-preserving float->uint; key = (ord << 32) | ~q => u64 max == (max value, min index)
__device__ __forceinline__ u32 f2ord(float f) {
    u32 u = __float_as_uint(f);
    return (u & 0x80000000u) ? ~u : (u | 0x80000000u);
}
__device__ __forceinline__ u64 mkkey(float g, int q) {
    return ((u64)f2ord(g) << 32) | (u32)(~(u32)q);
}
__device__ __forceinline__ int keyidx(u64 k) { return (int)(~(u32)k); }
__device__ __forceinline__ u64 umax64(u64 a, u64 b) { return a > b ? a : b; }
__device__ __forceinline__ u64 umin64(u64 a, u64 b) { return a > b ? b : a; }

// ---------------- kernel 1: per-column exact top-8 (indices out) ----------------
// 1600 blocks x 256 threads; each wave owns one (b,n) column
__global__ __launch_bounds__(256) void cand_kernel(
    const float* __restrict__ pred_boxes,   // [B,Q,4] cxcywh
    const float* __restrict__ target_boxes, // [B,N,4] xyxy
    u32* __restrict__ cands)                // [B*N*8] pred indices, descending key order
{
    const int blk = blockIdx.x;
    const int b = blk / 25;
    const int wave = threadIdx.x >> 6;
    const int lane = threadIdx.x & 63;
    const int n = (blk % 25) * 4 + wave;
    const int bn = b * N_ + n;

    const float* t = target_boxes + (size_t)bn * 4;
    float tx0 = t[0], ty0 = t[1], tx1 = t[2], ty1 = t[3];
    float ta = (tx1 - tx0) * (ty1 - ty0);

    const float4* pbv = (const float4*)(pred_boxes + (size_t)b * Q_ * 4);
    u64 a0 = 0, a1 = 0, a2 = 0, a3 = 0, a4 = 0, a5 = 0, a6 = 0, a7 = 0;  // sorted desc
    #pragma unroll
    for (int k = 0; k < KP; ++k) {
        int q = lane + (k << 6);
        if (q < Q_) {
            float4 c = pbv[q];
            float x0 = c.x - 0.5f * c.z, y0 = c.y - 0.5f * c.w;
            float x1 = c.x + 0.5f * c.z, y1 = c.y + 0.5f * c.w;
            float pa = (x1 - x0) * (y1 - y0);
            float g = giou_f(x0, y0, x1, y1, pa, tx0, ty0, tx1, ty1, ta);
            u64 kk = mkkey(g, q);
            a7 = umax64(a7, umin64(a6, kk));
            a6 = umax64(a6, umin64(a5, kk));
            a5 = umax64(a5, umin64(a4, kk));
            a4 = umax64(a4, umin64(a3, kk));
            a3 = umax64(a3, umin64(a2, kk));
            a2 = umax64(a2, umin64(a1, kk));
            a1 = umax64(a1, umin64(a0, kk));
            a0 = umax64(a0, kk);
        }
    }
    u32* outp = cands + (size_t)bn * K_;
    #pragma unroll
    for (int j = 0; j < K_; ++j) {
        u64 m = a0;
        #pragma unroll
        for (int off = 32; off >= 1; off >>= 1) {
            u64 o = __shfl_xor(m, off);
            if (o > m) m = o;
        }
        if (lane == 0) outp[j] = (u32)keyidx(m);
        if (a0 == m) {  // unique winner pops (keys embed distinct indices)
            a0 = a1; a1 = a2; a2 = a3; a3 = a4; a4 = a5; a5 = a6; a6 = a7; a7 = 0;
        }
    }
}

// ---- kernel 2: batched prefix-commit greedy resolve (single wave) + box loss ----
__global__ __launch_bounds__(64, 1) void match_kernel(
    const float* __restrict__ pred_boxes,
    const float* __restrict__ target_boxes,
    const u32*   __restrict__ cands,
    int* __restrict__ matches,      // [B*N]
    double* __restrict__ box_part)  // [B]
{
    const int b = blockIdx.x;
    const int lane = threadIdx.x;

    __shared__ float tx0s[N_], ty0s[N_], tx1s[N_], ty1s[N_], tas[N_];
    __shared__ int   s_ms[N_];
    __shared__ u32   s_used[32];    // 900-bit pred-used bitmap
    __shared__ u32   s_claim[1024]; // per-pred claim tags

    for (int i = lane; i < 1024; i += 64) s_claim[i] = 0u;
    if (lane < 32) s_used[lane] = 0u;
    for (int n = lane; n < N_; n += 64) {
        const float* t = target_boxes + (size_t)(b * N_ + n) * 4;
        float x0 = t[0], y0 = t[1], x1 = t[2], y1 = t[3];
        tx0s[n] = x0; ty0s[n] = y0; tx1s[n] = x1; ty1s[n] = y1;
        tas[n] = (x1 - x0) * (y1 - y0);
    }

    // transposed candidates: lane L owns column L (A) and column L+64 (B)
    int cA[K_], cB[K_];
    {
        const u32* p = cands + (size_t)(b * N_ + lane) * K_;
        #pragma unroll
        for (int j = 0; j < K_; ++j) cA[j] = (int)p[j];
    }
    #pragma unroll
    for (int j = 0; j < K_; ++j) cB[j] = 0;
    if (lane + 64 < N_) {
        const u32* p = cands + (size_t)(b * N_ + lane + 64) * K_;
        #pragma unroll
        for (int j = 0; j < K_; ++j) cB[j] = (int)p[j];
    }

    const float4* pbv = (const float4*)(pred_boxes + (size_t)b * Q_ * 4);
    bool activeA = true;
    bool activeB = (lane + 64 < N_);
    __syncthreads();

    int round = 1;
    while (__ballot(activeA) | __ballot(activeB)) {
        // --- phase 1: picks = first unused candidate (exact top-8 order) ---
        int pickA = -1, pickB = -1;
        #pragma unroll
        for (int j = 0; j < K_; ++j) {
            int ia = cA[j];
            bool availA = !((s_used[ia >> 5] >> (ia & 31)) & 1u);
            if (pickA < 0 && availA) pickA = ia;
            int ib = cB[j];
            bool availB = !((s_used[ib >> 5] >> (ib & 31)) & 1u);
            if (pickB < 0 && availB) pickB = ib;
        }
        // --- rare fallback: top-8 exhausted -> full masked argmax (one col at a time) ---
        u64 fm = __ballot(activeA && pickA < 0);
        while (fm) {
            int c = (int)__builtin_ctzll(fm);
            float tx0 = tx0s[c], ty0 = ty0s[c], tx1 = tx1s[c], ty1 = ty1s[c], ta = tas[c];
            u64 bk = 0ull;
            #pragma unroll
            for (int k = 0; k < KP; ++k) {
                int q = lane + (k << 6);
                if (q < Q_ && !((s_used[q >> 5] >> (q & 31)) & 1u)) {
                    float4 cc = pbv[q];
                    float x0 = cc.x - 0.5f * cc.z, y0 = cc.y - 0.5f * cc.w;
                    float x1 = cc.x + 0.5f * cc.z, y1 = cc.y + 0.5f * cc.w;
                    float pa = (x1 - x0) * (y1 - y0);
                    float g = giou_f(x0, y0, x1, y1, pa, tx0, ty0, tx1, ty1, ta);
                    u64 kk = mkkey(g, q);
                    if (kk > bk) bk = kk;
                }
            }
            #pragma unroll
            for (int off = 32; off >= 1; off >>= 1) {
                u64 o = __shfl_xor(bk, off);
                if (o > bk) bk = o;
            }
            if (lane == c) pickA = keyidx(bk);
            fm &= fm - 1;
        }
        fm = __ballot(activeB && pickB < 0);
        while (fm) {
            int c = (int)__builtin_ctzll(fm);
            int n = c + 64;
            float tx0 = tx0s[n], ty0 = ty0s[n], tx1 = tx1s[n], ty1 = ty1s[n], ta = tas[n];
            u64 bk = 0ull;
            #pragma unroll
            for (int k = 0; k < KP; ++k) {
                int q = lane + (k << 6);
                if (q < Q_ && !((s_used[q >> 5] >> (q & 31)) & 1u)) {
                    float4 cc = pbv[q];
                    float x0 = cc.x - 0.5f * cc.z, y0 = cc.y - 0.5f * cc.w;
                    float x1 = cc.x + 0.5f * cc.z, y1 = cc.y + 0.5f * cc.w;
                    float pa = (x1 - x0) * (y1 - y0);
                    float g = giou_f(x0, y0, x1, y1, pa, tx0, ty0, tx1, ty1, ta);
                    u64 kk = mkkey(g, q);
                    if (kk > bk) bk = kk;
                }
            }
            #pragma unroll
            for (int off = 32; off >= 1; off >>= 1) {
                u64 o = __shfl_xor(bk, off);
                if (o > bk) bk = o;
            }
            if (lane == c) pickB = keyidx(bk);
            fm &= fm - 1;
        }
        // --- phase 2: claims. tag = (round<<16)|(0xFFFF-col): max => smallest col, stale rounds lose ---
        u32 tagA = ((u32)round << 16) | (0xFFFFu - (u32)lane);
        u32 tagB = ((u32)round << 16) | (0xFFFFu - (u32)(lane + 64));
        if (activeA) atomicMax(&s_claim[pickA], tagA);
        if (activeB) atomicMax(&s_claim[pickB], tagB);
        __syncthreads();
        // --- phase 3: commit winners ---
        if (activeA && s_claim[pickA] == tagA) {
            s_ms[lane] = pickA;
            atomicOr(&s_used[pickA >> 5], 1u << (pickA & 31));
            activeA = false;
        }
        if (activeB && s_claim[pickB] == tagB) {
            s_ms[lane + 64] = pickB;
            atomicOr(&s_used[pickB >> 5], 1u << (pickB & 31));
            activeB = false;
        }
        __syncthreads();
        ++round;
    }

    // box losses: L1 + GIoU on matched pairs; publish matches
    double acc = 0.0;
    for (int n = lane; n < N_; n += 64) {
        int q = s_ms[n];
        matches[b * N_ + n] = q;
        float4 c = pbv[q];
        float tx0 = tx0s[n], ty0 = ty0s[n], tx1 = tx1s[n], ty1 = ty1s[n];
        float tcx = (tx0 + tx1) * 0.5f, tcy = (ty0 + ty1) * 0.5f;
        float tw = tx1 - tx0, th = ty1 - ty0;
        float l1 = fabsf(c.x - tcx) + fabsf(c.y - tcy) + fabsf(c.z - tw) + fabsf(c.w - th);
        float x0 = c.x - 0.5f * c.z, y0 = c.y - 0.5f * c.w;
        float x1 = c.x + 0.5f * c.z, y1 = c.y + 0.5f * c.w;
        float pa2 = (x1 - x0) * (y1 - y0);
        float g = giou_f(x0, y0, x1, y1, pa2, tx0, ty0, tx1, ty1, tas[n]);
        acc += (double)(BOX_W * l1) + (double)(GIOU_W * (1.0f - g));
    }
    #pragma unroll
    for (int off = 32; off >= 1; off >>= 1) acc += __shfl_xor(acc, off);
    if (lane == 0) box_part[b] = acc;
}

// ---------------- kernel 3: BCE over gathered logit rows ----------------
__global__ __launch_bounds__(64) void bce_kernel(
    const float* __restrict__ pred_logits,   // [B,Q,C]
    const int* __restrict__ target_labels,   // [B,N]
    const int* __restrict__ matches,         // [B*N]
    double* __restrict__ part)               // [B*N]
{
    const int bn = blockIdx.x;
    const int b = bn / N_;
    const int lane = threadIdx.x;
    const int q = matches[bn];
    const int lab = target_labels[bn];

    const float4* row = (const float4*)(pred_logits + ((size_t)(b * Q_ + q)) * C_);
    float4 v = row[lane];
    int base = lane * 4;
    float xs[4] = {v.x, v.y, v.z, v.w};
    double acc = 0.0;
    #pragma unroll
    for (int j = 0; j < 4; ++j) {
        float x = xs[j];
        float t = (base + j == lab) ? 1.0f : 0.0f;
        float term = fmaxf(x, 0.0f) - x * t + log1pf(expf(-fabsf(x)));
        acc += (double)term;
    }
    #pragma unroll
    for (int off = 32; off >= 1; off >>= 1) acc += __shfl_xor(acc, off);
    if (lane == 0) part[bn] = acc * (double)CLS_W;
}

// ---------------- kernel 4: final reduce ----------------
__global__ __launch_bounds__(256) void finalize_kernel(
    const double* __restrict__ bce_part,  // [B*N]
    const double* __restrict__ box_part,  // [B]
    float* __restrict__ out)
{
    const int tid = threadIdx.x;
    double acc = 0.0;
    for (int i = tid; i < B_ * N_; i += 256) acc += bce_part[i];
    if (tid < B_) acc += box_part[tid];
    __shared__ double red[256];
    red[tid] = acc;
    __syncthreads();
    #pragma unroll
    for (int s = 128; s >= 1; s >>= 1) {
        if (tid < s) red[tid] += red[tid + s];
        __syncthreads();
    }
    if (tid == 0) out[0] = (float)(red[0] / (double)(B_ * N_));
}

extern "C" void kernel_launch(void* const* d_in, const int* in_sizes, int n_in,
                              void* d_out, int out_size, void* d_ws, size_t ws_size,
                              hipStream_t stream) {
    const float* pred_boxes    = (const float*)d_in[0];
    const float* pred_logits   = (const float*)d_in[1];
    const float* target_boxes  = (const float*)d_in[2];
    const int*   target_labels = (const int*)d_in[3];
    float* out = (float*)d_out;

    char* ws = (char*)d_ws;
    u32*    cands    = (u32*)(ws);             // 6400*8*4 = 204800
    int*    matches  = (int*)(ws + 204800);    // 6400*4   = 25600
    double* bce_part = (double*)(ws + 230400); // 6400*8   = 51200
    double* box_part = (double*)(ws + 281600); // 64*8     = 512

    hipLaunchKernelGGL(cand_kernel, dim3(1600), dim3(256), 0, stream,
                       pred_boxes, target_boxes, cands);
    hipLaunchKernelGGL(match_kernel, dim3(B_), dim3(64), 0, stream,
                       pred_boxes, target_boxes, cands, matches, box_part);
    hipLaunchKernelGGL(bce_kernel, dim3(B_ * N_), dim3(64), 0, stream,
                       pred_logits, target_labels, matches, bce_part);
    hipLaunchKernelGGL(finalize_kernel, dim3(1), dim3(256), 0, stream,
                       bce_part, box_part, out);
}